// Round 4
// baseline (92.539 us; speedup 1.0000x reference)
//
#include <hip/hip_runtime.h>
#include <math.h>

#define B_    8
#define N_    1024
#define FIN   512
#define FOUT  256
#define ALPHA 0.2f
#define EPSV  1e-5f

typedef __attribute__((ext_vector_type(8))) short bf16x8;
typedef __attribute__((ext_vector_type(4))) float f32x4;

__device__ __forceinline__ short f2bf(float x) {
    unsigned u = __builtin_bit_cast(unsigned, x);
    u = (u + 0x7FFFu + ((u >> 16) & 1u)) >> 16;
    return (short)u;
}
__device__ __forceinline__ float bf2f(short s) {
    return __builtin_bit_cast(float, ((unsigned)(unsigned short)s) << 16);
}
__device__ __forceinline__ float gelu_exact(float x) {
    return 0.5f * x * (1.0f + erff(x * 0.70710678118654752f));
}

// ---------------------------------------------------------------------------
// k_prep: W (512x256 fp32 row-major) -> WT (256x512 bf16, [col][k]).
// ---------------------------------------------------------------------------
__global__ __launch_bounds__(256) void k_prep(const float* __restrict__ W,
                                              short* __restrict__ WT) {
    int id  = blockIdx.x * 256 + threadIdx.x;
    int col = id >> 7;
    int k4  = (id & 127) * 4;
    short4 v;
    v.x = f2bf(W[(k4 + 0) * FOUT + col]);
    v.y = f2bf(W[(k4 + 1) * FOUT + col]);
    v.z = f2bf(W[(k4 + 2) * FOUT + col]);
    v.w = f2bf(W[(k4 + 3) * FOUT + col]);
    *(short4*)(WT + (long)col * FIN + k4) = v;
}

// ---------------------------------------------------------------------------
// k_wh: Wh = h @ W via bf16 MFMA. Block = 256 thr / 4 waves; 16 rows;
// wave w -> cols w*64 (4 col-frags). Grid = 512. Fully unrolled K loop.
// Writes WhT bf16 ([b][col][row]) + fused F1/F2.
// ---------------------------------------------------------------------------
__global__ __launch_bounds__(256) void k_wh(const float* __restrict__ h,
                                            const short* __restrict__ WT,
                                            const float* __restrict__ a,
                                            short* __restrict__ WhT,
                                            float* __restrict__ F1,
                                            float* __restrict__ F2) {
    const int tid = threadIdx.x;
    const int w   = tid >> 6, l = tid & 63;
    const int lr  = l & 15, lq = l >> 4;
    const long row0 = (long)blockIdx.x * 16;
    const int colbase = w * 64;

    __shared__ float r1[4][16], r2[4][16];

    f32x4 acc[4] = {};
    const float* hrow = h + (row0 + lr) * FIN + lq * 8;

    #pragma unroll
    for (int k0 = 0; k0 < FIN; k0 += 32) {
        float4 v0 = *(const float4*)(hrow + k0);
        float4 v1 = *(const float4*)(hrow + k0 + 4);
        bf16x8 af;
        af[0] = f2bf(v0.x); af[1] = f2bf(v0.y); af[2] = f2bf(v0.z); af[3] = f2bf(v0.w);
        af[4] = f2bf(v1.x); af[5] = f2bf(v1.y); af[6] = f2bf(v1.z); af[7] = f2bf(v1.w);
        #pragma unroll
        for (int c = 0; c < 4; ++c) {
            const short* bp = WT + (long)(colbase + c * 16 + lr) * FIN + k0 + lq * 8;
            bf16x8 bf = *(const bf16x8*)bp;
            acc[c] = __builtin_amdgcn_mfma_f32_16x16x32_bf16(af, bf, acc[c], 0, 0, 0);
        }
    }

    const int b   = (int)(row0 >> 10);
    const int il0 = (int)(row0 & 1023);

    #pragma unroll
    for (int c = 0; c < 4; ++c) {
        short4 s;
        s.x = f2bf(acc[c][0]); s.y = f2bf(acc[c][1]);
        s.z = f2bf(acc[c][2]); s.w = f2bf(acc[c][3]);
        int col = colbase + c * 16 + lr;
        *(short4*)(WhT + ((long)b * FOUT + col) * N_ + il0 + lq * 4) = s;
    }

    float p1[4] = {0.f, 0.f, 0.f, 0.f}, p2[4] = {0.f, 0.f, 0.f, 0.f};
    #pragma unroll
    for (int c = 0; c < 4; ++c) {
        int col = colbase + c * 16 + lr;
        float a1v = a[col], a2v = a[FOUT + col];
        #pragma unroll
        for (int j = 0; j < 4; ++j) { p1[j] += acc[c][j] * a1v; p2[j] += acc[c][j] * a2v; }
    }
    #pragma unroll
    for (int off = 1; off < 16; off <<= 1) {
        #pragma unroll
        for (int j = 0; j < 4; ++j) {
            p1[j] += __shfl_xor(p1[j], off, 64);
            p2[j] += __shfl_xor(p2[j], off, 64);
        }
    }
    if (lr == 0) {
        #pragma unroll
        for (int j = 0; j < 4; ++j) { r1[w][lq * 4 + j] = p1[j]; r2[w][lq * 4 + j] = p2[j]; }
    }
    __syncthreads();
    if (tid < 16) {
        F1[row0 + tid] = r1[0][tid] + r1[1][tid] + r1[2][tid] + r1[3][tid];
        F2[row0 + tid] = r2[0][tid] + r2[1][tid] + r2[2][tid] + r2[3][tid];
    }
}

// ---------------------------------------------------------------------------
// k_attn: barrier-free masked attention via shift-invariant softmax (m=0).
//   w_ij = adj_ij>0 ? exp(leaky(f1_i + f2_j)) : 0   (bounded <= e^27: safe)
//   out_i = GELU(LN((sum_j w_ij * Wh_j) / sum_j w_ij))
// Block = 256 thr / 4 INDEPENDENT waves; wave = 32 rows x 64 cols.
// Grid = (8 batches, 32 rowgroups) -> blockIdx.x = batch pins each batch's
// 512 KB WhT slab to one XCD L2 (dispatch round-robins linear id % 8).
// Prologue (one barrier): ballot-compress adj (read ONCE, coalesced) into
// bits[32][16] u64 in LDS. Main loop: P generated in registers directly in
// A-frag layout (lane lr,lq owns k=lq*8+u), l summed from bf16-quantized w.
// ---------------------------------------------------------------------------
__global__ __launch_bounds__(256) void k_attn(const short* __restrict__ WhT,
                                              const float* __restrict__ adj,
                                              const float* __restrict__ F1,
                                              const float* __restrict__ F2,
                                              const float* __restrict__ gamma,
                                              const float* __restrict__ beta,
                                              float* __restrict__ out) {
    const int tid = threadIdx.x;
    const int b   = blockIdx.x;
    const int i0  = blockIdx.y * 32;
    const int w   = tid >> 6, l = tid & 63;
    const int lr  = l & 15, lq = l >> 4;

    __shared__ float f2s[N_];                         // 4 KB
    __shared__ unsigned long long bits[32][16];       // 4 KB
    __shared__ float lnp1[4][32], lnp2[4][32];        // 1 KB

    { int j = tid * 4; *(float4*)&f2s[j] = *(const float4*)(F2 + b * N_ + j); }

    // ---- prologue: adj -> bitmask (coalesced, read once) ----
    {
        const float* abase = adj + ((long)b * N_ + i0 + w * 8) * N_;
        for (int rr = 0; rr < 8; ++rr) {
            #pragma unroll
            for (int c = 0; c < 16; ++c) {
                float v = abase[(long)rr * N_ + c * 64 + l];
                unsigned long long m = __ballot(v > 0.f);
                if (l == 0) bits[w * 8 + rr][c] = m;
            }
        }
    }
    __syncthreads();

    const float f1v[2] = { F1[b * N_ + i0 + lr], F1[b * N_ + i0 + 16 + lr] };
    const int cw0 = w * 64;
    const short* __restrict__ whtb = WhT + ((long)b * FOUT + cw0) * N_;

    f32x4 acc[2][4] = {};
    float lsum[2] = {0.f, 0.f};

    for (int c = 0; c < 16; ++c) {
        const int k0 = c * 64;
        float f2k[16];
        *(float4*)&f2k[0]  = *(const float4*)&f2s[k0 + lq * 8];
        *(float4*)&f2k[4]  = *(const float4*)&f2s[k0 + lq * 8 + 4];
        *(float4*)&f2k[8]  = *(const float4*)&f2s[k0 + 32 + lq * 8];
        *(float4*)&f2k[12] = *(const float4*)&f2s[k0 + 32 + lq * 8 + 4];

        bf16x8 af[2][2];
        #pragma unroll
        for (int rf = 0; rf < 2; ++rf) {
            unsigned long long bb = bits[rf * 16 + lr][c] >> (lq * 8);
            unsigned mlo = (unsigned)bb;
            unsigned mhi = (unsigned)(bb >> 32);
            const float f1 = f1v[rf];
            float ls = 0.f;
            bf16x8 a0, a1;
            #pragma unroll
            for (int u = 0; u < 8; ++u) {
                float x0 = f1 + f2k[u];
                float x1 = f1 + f2k[8 + u];
                float t0 = fmaxf(x0, ALPHA * x0);
                float t1 = fmaxf(x1, ALPHA * x1);
                float e0 = ((mlo >> u) & 1u) ? __expf(t0) : 0.f;
                float e1 = ((mhi >> u) & 1u) ? __expf(t1) : 0.f;
                short s0 = f2bf(e0), s1 = f2bf(e1);
                a0[u] = s0; a1[u] = s1;
                ls += bf2f(s0) + bf2f(s1);
            }
            af[rf][0] = a0; af[rf][1] = a1;
            lsum[rf] += ls;
        }

        #pragma unroll
        for (int kq = 0; kq < 2; ++kq) {
            #pragma unroll
            for (int cf = 0; cf < 4; ++cf) {
                const short* bp = whtb + ((long)cf * 16 + lr) * N_ + k0 + kq * 32 + lq * 8;
                bf16x8 bf = *(const bf16x8*)bp;
                acc[0][cf] = __builtin_amdgcn_mfma_f32_16x16x32_bf16(af[0][kq], bf, acc[0][cf], 0, 0, 0);
                acc[1][cf] = __builtin_amdgcn_mfma_f32_16x16x32_bf16(af[1][kq], bf, acc[1][cf], 0, 0, 0);
            }
        }
    }

    // ---- l: reduce over lq (full row sums live at lane lr per rf) ----
    #pragma unroll
    for (int rf = 0; rf < 2; ++rf) {
        lsum[rf] += __shfl_xor(lsum[rf], 16, 64);
        lsum[rf] += __shfl_xor(lsum[rf], 32, 64);
    }
    // il for acc rows (local row = rf*16 + lq*4 + jj) via lane gather
    float il[2][4];
    #pragma unroll
    for (int rf = 0; rf < 2; ++rf)
        #pragma unroll
        for (int jj = 0; jj < 4; ++jj) {
            float r = __shfl(lsum[rf], lq * 4 + jj, 64);
            il[rf][jj] = (r > 0.f) ? 1.0f / r : 0.f;
        }

    // ---- LN partials over this wave's 64 cols ----
    #pragma unroll
    for (int rf = 0; rf < 2; ++rf) {
        float s1[4] = {0.f,0.f,0.f,0.f}, s2[4] = {0.f,0.f,0.f,0.f};
        #pragma unroll
        for (int cf = 0; cf < 4; ++cf)
            #pragma unroll
            for (int jj = 0; jj < 4; ++jj) {
                float v = acc[rf][cf][jj] * il[rf][jj];
                acc[rf][cf][jj] = v;
                s1[jj] += v;
                s2[jj] += v * v;
            }
        #pragma unroll
        for (int off = 1; off < 16; off <<= 1)
            #pragma unroll
            for (int jj = 0; jj < 4; ++jj) {
                s1[jj] += __shfl_xor(s1[jj], off, 64);
                s2[jj] += __shfl_xor(s2[jj], off, 64);
            }
        if (lr == 0) {
            #pragma unroll
            for (int jj = 0; jj < 4; ++jj) {
                lnp1[w][rf * 16 + lq * 4 + jj] = s1[jj];
                lnp2[w][rf * 16 + lq * 4 + jj] = s2[jj];
            }
        }
    }
    __syncthreads();

    // ---- LN + GELU + store ----
    #pragma unroll
    for (int rf = 0; rf < 2; ++rf)
        #pragma unroll
        for (int jj = 0; jj < 4; ++jj) {
            int row = rf * 16 + lq * 4 + jj;
            float t1 = lnp1[0][row] + lnp1[1][row] + lnp1[2][row] + lnp1[3][row];
            float t2 = lnp2[0][row] + lnp2[1][row] + lnp2[2][row] + lnp2[3][row];
            float mu   = t1 * (1.0f / FOUT);
            float rstd = rsqrtf(t2 * (1.0f / FOUT) - mu * mu + EPSV);
            #pragma unroll
            for (int cf = 0; cf < 4; ++cf) {
                int col = cw0 + cf * 16 + lr;
                out[((long)(b * N_ + i0 + row)) * FOUT + col] =
                    gelu_exact((acc[rf][cf][jj] - mu) * rstd * gamma[col] + beta[col]);
            }
        }
}

extern "C" void kernel_launch(void* const* d_in, const int* in_sizes, int n_in,
                              void* d_out, int out_size, void* d_ws, size_t ws_size,
                              hipStream_t stream) {
    const float* h     = (const float*)d_in[0];
    const float* adj   = (const float*)d_in[1];
    // d_in[2]=q_type, d_in[3]=pos : unused scalars
    const float* W     = (const float*)d_in[4];
    const float* a     = (const float*)d_in[5];
    const float* gamma = (const float*)d_in[6];
    const float* beta  = (const float*)d_in[7];
    float* out = (float*)d_out;

    short* WhT = (short*)d_ws;                         // 8*256*1024 bf16 = 4 MB
    short* WT  = WhT + (size_t)B_ * FOUT * N_;         // 256*512 bf16 = 256 KB
    float* F1  = (float*)(WT + (size_t)FOUT * FIN);    // 8192 fp32
    float* F2  = F1 + (size_t)B_ * N_;                 // 8192 fp32

    k_prep<<<dim3(128), 256, 0, stream>>>(W, WT);
    k_wh<<<dim3(B_ * N_ / 16), 256, 0, stream>>>(h, WT, a, WhT, F1, F2);
    k_attn<<<dim3(B_, N_ / 32), 256, 0, stream>>>(WhT, adj, F1, F2, gamma, beta, out);
}

// Round 5
// 90.277 us; speedup vs baseline: 1.0251x; 1.0251x over previous
//
#include <hip/hip_runtime.h>
#include <math.h>

#define B_    8
#define N_    1024
#define FIN   512
#define FOUT  256
#define ALPHA 0.2f
#define EPSV  1e-5f

typedef __attribute__((ext_vector_type(8))) short bf16x8;
typedef __attribute__((ext_vector_type(4))) float f32x4;

__device__ __forceinline__ short f2bf(float x) {          // RNE (weights path)
    unsigned u = __builtin_bit_cast(unsigned, x);
    u = (u + 0x7FFFu + ((u >> 16) & 1u)) >> 16;
    return (short)u;
}
__device__ __forceinline__ short f2bf_fast(float x) {     // round-half-up (P path)
    unsigned u = __builtin_bit_cast(unsigned, x);
    return (short)((u + 0x8000u) >> 16);
}
__device__ __forceinline__ float bf2f(short s) {
    return __builtin_bit_cast(float, ((unsigned)(unsigned short)s) << 16);
}
__device__ __forceinline__ float gelu_exact(float x) {
    return 0.5f * x * (1.0f + erff(x * 0.70710678118654752f));
}

// ---------------------------------------------------------------------------
// k_prep: W (512x256 fp32 row-major) -> WT (256x512 bf16, [col][k]).
// ---------------------------------------------------------------------------
__global__ __launch_bounds__(256) void k_prep(const float* __restrict__ W,
                                              short* __restrict__ WT) {
    int id  = blockIdx.x * 256 + threadIdx.x;
    int col = id >> 7;
    int k4  = (id & 127) * 4;
    short4 v;
    v.x = f2bf(W[(k4 + 0) * FOUT + col]);
    v.y = f2bf(W[(k4 + 1) * FOUT + col]);
    v.z = f2bf(W[(k4 + 2) * FOUT + col]);
    v.w = f2bf(W[(k4 + 3) * FOUT + col]);
    *(short4*)(WT + (long)col * FIN + k4) = v;
}

// ---------------------------------------------------------------------------
// k_wh: Wh = h @ W via bf16 MFMA. Block = 256 thr / 4 waves; 16 rows;
// wave w -> cols w*64 (4 col-frags). Grid = 512. Writes WhT bf16
// ([b][col][row]) + fused F1/F2.  (unchanged from R4 — it was ~9 us)
// ---------------------------------------------------------------------------
__global__ __launch_bounds__(256) void k_wh(const float* __restrict__ h,
                                            const short* __restrict__ WT,
                                            const float* __restrict__ a,
                                            short* __restrict__ WhT,
                                            float* __restrict__ F1,
                                            float* __restrict__ F2) {
    const int tid = threadIdx.x;
    const int w   = tid >> 6, l = tid & 63;
    const int lr  = l & 15, lq = l >> 4;
    const long row0 = (long)blockIdx.x * 16;
    const int colbase = w * 64;

    __shared__ float r1[4][16], r2[4][16];

    f32x4 acc[4] = {};
    const float* hrow = h + (row0 + lr) * FIN + lq * 8;

    #pragma unroll
    for (int k0 = 0; k0 < FIN; k0 += 32) {
        float4 v0 = *(const float4*)(hrow + k0);
        float4 v1 = *(const float4*)(hrow + k0 + 4);
        bf16x8 af;
        af[0] = f2bf(v0.x); af[1] = f2bf(v0.y); af[2] = f2bf(v0.z); af[3] = f2bf(v0.w);
        af[4] = f2bf(v1.x); af[5] = f2bf(v1.y); af[6] = f2bf(v1.z); af[7] = f2bf(v1.w);
        #pragma unroll
        for (int c = 0; c < 4; ++c) {
            const short* bp = WT + (long)(colbase + c * 16 + lr) * FIN + k0 + lq * 8;
            bf16x8 bf = *(const bf16x8*)bp;
            acc[c] = __builtin_amdgcn_mfma_f32_16x16x32_bf16(af, bf, acc[c], 0, 0, 0);
        }
    }

    const int b   = (int)(row0 >> 10);
    const int il0 = (int)(row0 & 1023);

    #pragma unroll
    for (int c = 0; c < 4; ++c) {
        short4 s;
        s.x = f2bf(acc[c][0]); s.y = f2bf(acc[c][1]);
        s.z = f2bf(acc[c][2]); s.w = f2bf(acc[c][3]);
        int col = colbase + c * 16 + lr;
        *(short4*)(WhT + ((long)b * FOUT + col) * N_ + il0 + lq * 4) = s;
    }

    float p1[4] = {0.f, 0.f, 0.f, 0.f}, p2[4] = {0.f, 0.f, 0.f, 0.f};
    #pragma unroll
    for (int c = 0; c < 4; ++c) {
        int col = colbase + c * 16 + lr;
        float a1v = a[col], a2v = a[FOUT + col];
        #pragma unroll
        for (int j = 0; j < 4; ++j) { p1[j] += acc[c][j] * a1v; p2[j] += acc[c][j] * a2v; }
    }
    #pragma unroll
    for (int off = 1; off < 16; off <<= 1) {
        #pragma unroll
        for (int j = 0; j < 4; ++j) {
            p1[j] += __shfl_xor(p1[j], off, 64);
            p2[j] += __shfl_xor(p2[j], off, 64);
        }
    }
    if (lr == 0) {
        #pragma unroll
        for (int j = 0; j < 4; ++j) { r1[w][lq * 4 + j] = p1[j]; r2[w][lq * 4 + j] = p2[j]; }
    }
    __syncthreads();
    if (tid < 16) {
        F1[row0 + tid] = r1[0][tid] + r1[1][tid] + r1[2][tid] + r1[3][tid];
        F2[row0 + tid] = r2[0][tid] + r2[1][tid] + r2[2][tid] + r2[3][tid];
    }
}

// ---------------------------------------------------------------------------
// k_attn: barrier-light masked attention, shift-invariant softmax (m=0):
//   w_ij = adj_ij>0 ? exp(leaky(f1_i+f2_j)) : 0  (<= e^27, fp32-safe)
// Block = 256 thr / 4 waves; block tile = 16 rows x 256 cols; wave w = cols
// w*64..+63 (rows SHARED -> adj read once device-wide). Grid = (8, 64):
// blockIdx.x = batch -> linear id % 8 pins each batch's WhT slab to one XCD.
// Prologue: 4 rows/wave ballot-compress adj into LDS bits[16][17] (padded ->
// conflict-free). Main loop (no barriers): P generated in registers in
// A-frag layout, l summed from the bf16-quantized P fed to MFMA.
// ---------------------------------------------------------------------------
__global__ __launch_bounds__(256) void k_attn(const short* __restrict__ WhT,
                                              const float* __restrict__ adj,
                                              const float* __restrict__ F1,
                                              const float* __restrict__ F2,
                                              const float* __restrict__ gamma,
                                              const float* __restrict__ beta,
                                              float* __restrict__ out) {
    const int tid = threadIdx.x;
    const int b   = blockIdx.x;
    const int i0  = blockIdx.y * 16;
    const int w   = tid >> 6, l = tid & 63;
    const int lr  = l & 15, lq = l >> 4;

    __shared__ float f2s[N_];                       // 4 KB
    __shared__ unsigned long long bits[16][17];     // 2.1 KB, padded
    __shared__ float lnp1[4][16], lnp2[4][16];      // 0.5 KB

    { int j = tid * 4; *(float4*)&f2s[j] = *(const float4*)(F2 + b * N_ + j); }

    // ---- prologue: adj -> bitmask (read once, coalesced 256B/ballot) ----
    {
        const float* abase = adj + ((long)b * N_ + i0 + w * 4) * N_;
        #pragma unroll
        for (int rr = 0; rr < 4; ++rr) {
            #pragma unroll
            for (int c = 0; c < 16; ++c) {
                float v = abase[(long)rr * N_ + c * 64 + l];
                unsigned long long mm = __ballot(v > 0.f);
                if (l == 0) bits[w * 4 + rr][c] = mm;
            }
        }
    }
    __syncthreads();

    const float f1v = F1[b * N_ + i0 + lr];
    const int cw0 = w * 64;
    const short* __restrict__ whtb = WhT + ((long)b * FOUT + cw0) * N_;

    f32x4 acc[4] = {};
    float lsum = 0.f;

    #pragma unroll 4
    for (int c = 0; c < 16; ++c) {
        const int k0 = c * 64;
        unsigned long long bb = bits[lr][c];
        unsigned m0 = (unsigned)(bb >> (lq * 8)) & 0xFFu;
        unsigned m1 = (unsigned)(bb >> (32 + lq * 8)) & 0xFFu;

        float f2k[16];
        *(float4*)&f2k[0]  = *(const float4*)&f2s[k0 + lq * 8];
        *(float4*)&f2k[4]  = *(const float4*)&f2s[k0 + lq * 8 + 4];
        *(float4*)&f2k[8]  = *(const float4*)&f2s[k0 + 32 + lq * 8];
        *(float4*)&f2k[12] = *(const float4*)&f2s[k0 + 32 + lq * 8 + 4];

        bf16x8 a0, a1;
        float ls = 0.f;
        #pragma unroll
        for (int u = 0; u < 8; ++u) {
            float x0 = f1v + f2k[u];
            float x1 = f1v + f2k[8 + u];
            float t0 = fmaxf(x0, ALPHA * x0);
            float t1 = fmaxf(x1, ALPHA * x1);
            float e0 = ((m0 >> u) & 1u) ? __expf(t0) : 0.f;
            float e1 = ((m1 >> u) & 1u) ? __expf(t1) : 0.f;
            short s0 = f2bf_fast(e0), s1 = f2bf_fast(e1);
            a0[u] = s0; a1[u] = s1;
            ls += bf2f(s0) + bf2f(s1);
        }
        lsum += ls;

        #pragma unroll
        for (int cf = 0; cf < 4; ++cf) {
            const short* bp0 = whtb + ((long)cf * 16 + lr) * N_ + k0 + lq * 8;
            bf16x8 bf0 = *(const bf16x8*)bp0;
            bf16x8 bf1 = *(const bf16x8*)(bp0 + 32);
            acc[cf] = __builtin_amdgcn_mfma_f32_16x16x32_bf16(a0, bf0, acc[cf], 0, 0, 0);
            acc[cf] = __builtin_amdgcn_mfma_f32_16x16x32_bf16(a1, bf1, acc[cf], 0, 0, 0);
        }
    }

    // ---- row sums: combine the 4 lq partial copies (row lr) ----
    lsum += __shfl_xor(lsum, 16, 64);
    lsum += __shfl_xor(lsum, 32, 64);
    // il for acc rows (local row = lq*4+jj lives at lane lq*4+jj)
    float il[4];
    #pragma unroll
    for (int jj = 0; jj < 4; ++jj) {
        float r = __shfl(lsum, lq * 4 + jj, 64);
        il[jj] = (r > 0.f) ? 1.0f / r : 0.f;
    }

    // ---- LN partials over this wave's 64 cols ----
    float s1[4] = {0.f,0.f,0.f,0.f}, s2[4] = {0.f,0.f,0.f,0.f};
    #pragma unroll
    for (int cf = 0; cf < 4; ++cf)
        #pragma unroll
        for (int jj = 0; jj < 4; ++jj) {
            float v = acc[cf][jj] * il[jj];
            acc[cf][jj] = v;
            s1[jj] += v;
            s2[jj] += v * v;
        }
    #pragma unroll
    for (int off = 1; off < 16; off <<= 1)
        #pragma unroll
        for (int jj = 0; jj < 4; ++jj) {
            s1[jj] += __shfl_xor(s1[jj], off, 64);
            s2[jj] += __shfl_xor(s2[jj], off, 64);
        }
    if (lr == 0) {
        #pragma unroll
        for (int jj = 0; jj < 4; ++jj) {
            lnp1[w][lq * 4 + jj] = s1[jj];
            lnp2[w][lq * 4 + jj] = s2[jj];
        }
    }
    __syncthreads();

    // ---- LN + GELU + store ----
    #pragma unroll
    for (int jj = 0; jj < 4; ++jj) {
        int row = lq * 4 + jj;
        float t1 = lnp1[0][row] + lnp1[1][row] + lnp1[2][row] + lnp1[3][row];
        float t2 = lnp2[0][row] + lnp2[1][row] + lnp2[2][row] + lnp2[3][row];
        float mu   = t1 * (1.0f / FOUT);
        float rstd = rsqrtf(t2 * (1.0f / FOUT) - mu * mu + EPSV);
        #pragma unroll
        for (int cf = 0; cf < 4; ++cf) {
            int col = cw0 + cf * 16 + lr;
            out[((long)(b * N_ + i0 + row)) * FOUT + col] =
                gelu_exact((acc[cf][jj] - mu) * rstd * gamma[col] + beta[col]);
        }
    }
}

extern "C" void kernel_launch(void* const* d_in, const int* in_sizes, int n_in,
                              void* d_out, int out_size, void* d_ws, size_t ws_size,
                              hipStream_t stream) {
    const float* h     = (const float*)d_in[0];
    const float* adj   = (const float*)d_in[1];
    // d_in[2]=q_type, d_in[3]=pos : unused scalars
    const float* W     = (const float*)d_in[4];
    const float* a     = (const float*)d_in[5];
    const float* gamma = (const float*)d_in[6];
    const float* beta  = (const float*)d_in[7];
    float* out = (float*)d_out;

    short* WhT = (short*)d_ws;                         // 8*256*1024 bf16 = 4 MB
    short* WT  = WhT + (size_t)B_ * FOUT * N_;         // 256*512 bf16 = 256 KB
    float* F1  = (float*)(WT + (size_t)FOUT * FIN);    // 8192 fp32
    float* F2  = F1 + (size_t)B_ * N_;                 // 8192 fp32

    k_prep<<<dim3(128), 256, 0, stream>>>(W, WT);
    k_wh<<<dim3(B_ * N_ / 16), 256, 0, stream>>>(h, WT, a, WhT, F1, F2);
    k_attn<<<dim3(B_, N_ / 16), 256, 0, stream>>>(WhT, adj, F1, F2, gamma, beta, out);
}

// Round 6
// 83.896 us; speedup vs baseline: 1.1030x; 1.0761x over previous
//
#include <hip/hip_runtime.h>
#include <math.h>

#define B_    8
#define N_    1024
#define FIN   512
#define FOUT  256
#define ALPHA 0.2f
#define EPSV  1e-5f

typedef __attribute__((ext_vector_type(8))) short bf16x8;
typedef __attribute__((ext_vector_type(4))) float f32x4;

__device__ __forceinline__ short f2bf(float x) {          // RNE
    unsigned u = __builtin_bit_cast(unsigned, x);
    u = (u + 0x7FFFu + ((u >> 16) & 1u)) >> 16;
    return (short)u;
}
__device__ __forceinline__ short f2bf_fast(float x) {     // round-half-up (P path)
    unsigned u = __builtin_bit_cast(unsigned, x);
    return (short)((u + 0x8000u) >> 16);
}
__device__ __forceinline__ float bf2f(short s) {
    return __builtin_bit_cast(float, ((unsigned)(unsigned short)s) << 16);
}
__device__ __forceinline__ float gelu_exact(float x) {
    return 0.5f * x * (1.0f + erff(x * 0.70710678118654752f));
}

// ---------------------------------------------------------------------------
// k_prep: W (512x256 fp32 row-major) -> WT (256x512 bf16, [col][k]).
// ---------------------------------------------------------------------------
__global__ __launch_bounds__(256) void k_prep(const float* __restrict__ W,
                                              short* __restrict__ WT) {
    int id  = blockIdx.x * 256 + threadIdx.x;
    int col = id >> 7;
    int k4  = (id & 127) * 4;
    short4 v;
    v.x = f2bf(W[(k4 + 0) * FOUT + col]);
    v.y = f2bf(W[(k4 + 1) * FOUT + col]);
    v.z = f2bf(W[(k4 + 2) * FOUT + col]);
    v.w = f2bf(W[(k4 + 3) * FOUT + col]);
    *(short4*)(WT + (long)col * FIN + k4) = v;
}

// ---------------------------------------------------------------------------
// k_wh: Wh = h @ W via bf16 MFMA. Block = 256 thr / 4 waves; 16 rows;
// wave w -> cols w*64 (4 col-frags). Grid = 512. Writes WhT bf16
// ([b][col][row]) + fused F1/F2.  (proven ~9 us)
// ---------------------------------------------------------------------------
__global__ __launch_bounds__(256) void k_wh(const float* __restrict__ h,
                                            const short* __restrict__ WT,
                                            const float* __restrict__ a,
                                            short* __restrict__ WhT,
                                            float* __restrict__ F1,
                                            float* __restrict__ F2) {
    const int tid = threadIdx.x;
    const int w   = tid >> 6, l = tid & 63;
    const int lr  = l & 15, lq = l >> 4;
    const long row0 = (long)blockIdx.x * 16;
    const int colbase = w * 64;

    __shared__ float r1[4][16], r2[4][16];

    f32x4 acc[4] = {};
    const float* hrow = h + (row0 + lr) * FIN + lq * 8;

    #pragma unroll
    for (int k0 = 0; k0 < FIN; k0 += 32) {
        float4 v0 = *(const float4*)(hrow + k0);
        float4 v1 = *(const float4*)(hrow + k0 + 4);
        bf16x8 af;
        af[0] = f2bf(v0.x); af[1] = f2bf(v0.y); af[2] = f2bf(v0.z); af[3] = f2bf(v0.w);
        af[4] = f2bf(v1.x); af[5] = f2bf(v1.y); af[6] = f2bf(v1.z); af[7] = f2bf(v1.w);
        #pragma unroll
        for (int c = 0; c < 4; ++c) {
            const short* bp = WT + (long)(colbase + c * 16 + lr) * FIN + k0 + lq * 8;
            bf16x8 bf = *(const bf16x8*)bp;
            acc[c] = __builtin_amdgcn_mfma_f32_16x16x32_bf16(af, bf, acc[c], 0, 0, 0);
        }
    }

    const int b   = (int)(row0 >> 10);
    const int il0 = (int)(row0 & 1023);

    #pragma unroll
    for (int c = 0; c < 4; ++c) {
        short4 s;
        s.x = f2bf(acc[c][0]); s.y = f2bf(acc[c][1]);
        s.z = f2bf(acc[c][2]); s.w = f2bf(acc[c][3]);
        int col = colbase + c * 16 + lr;
        *(short4*)(WhT + ((long)b * FOUT + col) * N_ + il0 + lq * 4) = s;
    }

    float p1[4] = {0.f, 0.f, 0.f, 0.f}, p2[4] = {0.f, 0.f, 0.f, 0.f};
    #pragma unroll
    for (int c = 0; c < 4; ++c) {
        int col = colbase + c * 16 + lr;
        float a1v = a[col], a2v = a[FOUT + col];
        #pragma unroll
        for (int j = 0; j < 4; ++j) { p1[j] += acc[c][j] * a1v; p2[j] += acc[c][j] * a2v; }
    }
    #pragma unroll
    for (int off = 1; off < 16; off <<= 1) {
        #pragma unroll
        for (int j = 0; j < 4; ++j) {
            p1[j] += __shfl_xor(p1[j], off, 64);
            p2[j] += __shfl_xor(p2[j], off, 64);
        }
    }
    if (lr == 0) {
        #pragma unroll
        for (int j = 0; j < 4; ++j) { r1[w][lq * 4 + j] = p1[j]; r2[w][lq * 4 + j] = p2[j]; }
    }
    __syncthreads();
    if (tid < 16) {
        F1[row0 + tid] = r1[0][tid] + r1[1][tid] + r1[2][tid] + r1[3][tid];
        F2[row0 + tid] = r2[0][tid] + r2[1][tid] + r2[2][tid] + r2[3][tid];
    }
}

// ---------------------------------------------------------------------------
// k_pgen: P[i][j] = adj ? exp(leaky(f1_i + f2_j)) : 0  (bf16, m=0 softmax,
// <= e^27 so fp32-safe), plus fp32 row sums l (summed from the bf16-quantized
// values actually fed to the GEMM). Pure streaming: adj read once, coalesced.
// Block = 256 thr = 8 rows x 32 lanes; thread owns 32 j's (4 x float4,
// interleaved so each 32-lane group's loads are 512B contiguous). Grid = 1024.
// ---------------------------------------------------------------------------
__global__ __launch_bounds__(256) void k_pgen(const float* __restrict__ adj,
                                              const float* __restrict__ F1,
                                              const float* __restrict__ F2,
                                              short* __restrict__ P,
                                              float* __restrict__ lrow) {
    const int tid = threadIdx.x;
    const long grow = (long)blockIdx.x * 8 + (tid >> 5);   // global row b*1024+i
    const int  b    = (int)(grow >> 10);
    const int  c    = tid & 31;

    const float f1 = F1[grow];
    const float* __restrict__ arow = adj + grow * N_;
    const float* __restrict__ f2b  = F2 + (long)b * N_;
    short* __restrict__ prow = P + grow * N_;

    float ls = 0.f;
    #pragma unroll
    for (int u = 0; u < 8; ++u) {
        const int j = u * 128 + c * 4;
        float4 av  = *(const float4*)(arow + j);
        float4 f2v = *(const float4*)(f2b + j);
        float xv[4] = {f2v.x, f2v.y, f2v.z, f2v.w};
        float aa[4] = {av.x, av.y, av.z, av.w};
        short4 s;
        short* sp = (short*)&s;
        #pragma unroll
        for (int q = 0; q < 4; ++q) {
            float x = f1 + xv[q];
            float t = fmaxf(x, ALPHA * x);
            float e = (aa[q] > 0.f) ? __expf(t) : 0.f;
            short sv = f2bf_fast(e);
            sp[q] = sv;
            ls += bf2f(sv);
        }
        *(short4*)(prow + j) = s;
    }
    #pragma unroll
    for (int off = 1; off < 32; off <<= 1) ls += __shfl_xor(ls, off, 64);
    if (c == 0) lrow[grow] = ls;
}

// ---------------------------------------------------------------------------
// k_pv: h_prime = (P @ Wh) / l, + LayerNorm + GELU. Dense bf16 MFMA GEMM,
// exactly k_wh's structure with K=1024. Block = 256 thr / 4 waves; 16 rows;
// wave w -> cols w*64 (4 col-frags). Grid = (8, 64): blockIdx.x = batch ->
// linear id % 8 pins each batch's 512KB WhT slab to one XCD L2.
// ---------------------------------------------------------------------------
__global__ __launch_bounds__(256) void k_pv(const short* __restrict__ P,
                                            const short* __restrict__ WhT,
                                            const float* __restrict__ lrow,
                                            const float* __restrict__ gamma,
                                            const float* __restrict__ beta,
                                            float* __restrict__ out) {
    const int tid = threadIdx.x;
    const int b   = blockIdx.x;
    const int i0  = blockIdx.y * 16;
    const int w   = tid >> 6, l = tid & 63;
    const int lr  = l & 15, lq = l >> 4;
    const int cw0 = w * 64;

    __shared__ float lnp1[4][16], lnp2[4][16];

    const short* __restrict__ prow = P + ((long)b * N_ + i0 + lr) * N_ + lq * 8;
    const short* __restrict__ whtb = WhT + ((long)b * FOUT + cw0) * N_ + lq * 8;

    f32x4 acc[4] = {};

    #pragma unroll 4
    for (int k0 = 0; k0 < N_; k0 += 32) {
        bf16x8 af = *(const bf16x8*)(prow + k0);
        #pragma unroll
        for (int cf = 0; cf < 4; ++cf) {
            bf16x8 bf = *(const bf16x8*)(whtb + ((long)cf * 16 + lr) * N_ + k0);
            acc[cf] = __builtin_amdgcn_mfma_f32_16x16x32_bf16(af, bf, acc[cf], 0, 0, 0);
        }
    }

    // 1/l for this thread's acc rows (local row = lq*4 + jj)
    float il[4];
    #pragma unroll
    for (int jj = 0; jj < 4; ++jj) {
        float r = lrow[(long)b * N_ + i0 + lq * 4 + jj];
        il[jj] = (r > 0.f) ? 1.0f / r : 0.f;
    }

    // LN partials over this wave's 64 cols
    float s1[4] = {0.f,0.f,0.f,0.f}, s2[4] = {0.f,0.f,0.f,0.f};
    #pragma unroll
    for (int cf = 0; cf < 4; ++cf)
        #pragma unroll
        for (int jj = 0; jj < 4; ++jj) {
            float v = acc[cf][jj] * il[jj];
            acc[cf][jj] = v;
            s1[jj] += v;
            s2[jj] += v * v;
        }
    #pragma unroll
    for (int off = 1; off < 16; off <<= 1)
        #pragma unroll
        for (int jj = 0; jj < 4; ++jj) {
            s1[jj] += __shfl_xor(s1[jj], off, 64);
            s2[jj] += __shfl_xor(s2[jj], off, 64);
        }
    if (lr == 0) {
        #pragma unroll
        for (int jj = 0; jj < 4; ++jj) {
            lnp1[w][lq * 4 + jj] = s1[jj];
            lnp2[w][lq * 4 + jj] = s2[jj];
        }
    }
    __syncthreads();

    // LN + GELU + store
    #pragma unroll
    for (int jj = 0; jj < 4; ++jj) {
        int row = lq * 4 + jj;
        float t1 = lnp1[0][row] + lnp1[1][row] + lnp1[2][row] + lnp1[3][row];
        float t2 = lnp2[0][row] + lnp2[1][row] + lnp2[2][row] + lnp2[3][row];
        float mu   = t1 * (1.0f / FOUT);
        float rstd = rsqrtf(t2 * (1.0f / FOUT) - mu * mu + EPSV);
        #pragma unroll
        for (int cf = 0; cf < 4; ++cf) {
            int col = cw0 + cf * 16 + lr;
            out[((long)(b * N_ + i0 + row)) * FOUT + col] =
                gelu_exact((acc[cf][jj] - mu) * rstd * gamma[col] + beta[col]);
        }
    }
}

extern "C" void kernel_launch(void* const* d_in, const int* in_sizes, int n_in,
                              void* d_out, int out_size, void* d_ws, size_t ws_size,
                              hipStream_t stream) {
    const float* h     = (const float*)d_in[0];
    const float* adj   = (const float*)d_in[1];
    // d_in[2]=q_type, d_in[3]=pos : unused scalars
    const float* W     = (const float*)d_in[4];
    const float* a     = (const float*)d_in[5];
    const float* gamma = (const float*)d_in[6];
    const float* beta  = (const float*)d_in[7];
    float* out = (float*)d_out;

    // workspace layout (~20.6 MB)
    short* WhT  = (short*)d_ws;                        // 8*256*1024 bf16 = 4 MB
    short* WT   = WhT + (size_t)B_ * FOUT * N_;        // 256*512 bf16 = 256 KB
    short* P    = WT + (size_t)FOUT * FIN;             // 8*1024*1024 bf16 = 16 MB
    float* F1   = (float*)(P + (size_t)B_ * N_ * N_);  // 8192 fp32
    float* F2   = F1 + (size_t)B_ * N_;                // 8192 fp32
    float* lrow = F2 + (size_t)B_ * N_;                // 8192 fp32

    k_prep<<<dim3(128), 256, 0, stream>>>(W, WT);
    k_wh  <<<dim3(B_ * N_ / 16), 256, 0, stream>>>(h, WT, a, WhT, F1, F2);
    k_pgen<<<dim3(B_ * N_ / 8), 256, 0, stream>>>(adj, F1, F2, P, lrow);
    k_pv  <<<dim3(B_, N_ / 16), 256, 0, stream>>>(P, WhT, lrow, gamma, beta, out);
}

// Round 7
// 78.377 us; speedup vs baseline: 1.1807x; 1.0704x over previous
//
#include <hip/hip_runtime.h>
#include <math.h>

#define B_    8
#define N_    1024
#define FIN   512
#define FOUT  256
#define ALPHA 0.2f
#define EPSV  1e-5f

typedef __attribute__((ext_vector_type(8))) short bf16x8;
typedef __attribute__((ext_vector_type(4))) float f32x4;

__device__ __forceinline__ short f2bf(float x) {          // RNE
    unsigned u = __builtin_bit_cast(unsigned, x);
    u = (u + 0x7FFFu + ((u >> 16) & 1u)) >> 16;
    return (short)u;
}
__device__ __forceinline__ short f2bf_fast(float x) {     // round-half-up (P path)
    unsigned u = __builtin_bit_cast(unsigned, x);
    return (short)((u + 0x8000u) >> 16);
}
__device__ __forceinline__ float bf2f(short s) {
    return __builtin_bit_cast(float, ((unsigned)(unsigned short)s) << 16);
}
__device__ __forceinline__ float gelu_exact(float x) {
    return 0.5f * x * (1.0f + erff(x * 0.70710678118654752f));
}

// Fragment-linear chunk layout (1 KB = 64 lanes x 16B):
//   Apack[b][m16][kt][l][u8] : lane l=(lq*16+lr) holds P[m16*16+lr][kt*32+lq*8+u]
//   Bpack[b][n16][kt][l][u8] : lane l=(lq*16+lr) holds Wh[kt*32+lq*8+u][n16*16+lr]

// ---------------------------------------------------------------------------
// k_prep: W (512x256 fp32 row-major) -> WT (256x512 bf16, [col][k]).
// ---------------------------------------------------------------------------
__global__ __launch_bounds__(256) void k_prep(const float* __restrict__ W,
                                              short* __restrict__ WT) {
    int id  = blockIdx.x * 256 + threadIdx.x;
    int col = id >> 7;
    int k4  = (id & 127) * 4;
    short4 v;
    v.x = f2bf(W[(k4 + 0) * FOUT + col]);
    v.y = f2bf(W[(k4 + 1) * FOUT + col]);
    v.z = f2bf(W[(k4 + 2) * FOUT + col]);
    v.w = f2bf(W[(k4 + 3) * FOUT + col]);
    *(short4*)(WT + (long)col * FIN + k4) = v;
}

// ---------------------------------------------------------------------------
// k_wh: Wh = h @ W via bf16 MFMA; writes Bpack (fragment-linear, coalesced
// 512B/instr short4 stores derived from the C/D layout) + fused F1/F2.
// Block = 256 thr / 4 waves; 16 node-rows (= K-dim of PV); grid = 512.
// ---------------------------------------------------------------------------
__global__ __launch_bounds__(256) void k_wh(const float* __restrict__ h,
                                            const short* __restrict__ WT,
                                            const float* __restrict__ a,
                                            short* __restrict__ Bpack,
                                            float* __restrict__ F1,
                                            float* __restrict__ F2) {
    const int tid = threadIdx.x;
    const int w   = tid >> 6, l = tid & 63;
    const int lr  = l & 15, lq = l >> 4;
    const long row0 = (long)blockIdx.x * 16;
    const int colbase = w * 64;

    __shared__ float r1[4][16], r2[4][16];

    f32x4 acc[4] = {};
    const float* hrow = h + (row0 + lr) * FIN + lq * 8;

    #pragma unroll
    for (int k0 = 0; k0 < FIN; k0 += 32) {
        float4 v0 = *(const float4*)(hrow + k0);
        float4 v1 = *(const float4*)(hrow + k0 + 4);
        bf16x8 af;
        af[0] = f2bf(v0.x); af[1] = f2bf(v0.y); af[2] = f2bf(v0.z); af[3] = f2bf(v0.w);
        af[4] = f2bf(v1.x); af[5] = f2bf(v1.y); af[6] = f2bf(v1.z); af[7] = f2bf(v1.w);
        #pragma unroll
        for (int c = 0; c < 4; ++c) {
            const short* bp = WT + (long)(colbase + c * 16 + lr) * FIN + k0 + lq * 8;
            bf16x8 bf = *(const bf16x8*)bp;
            acc[c] = __builtin_amdgcn_mfma_f32_16x16x32_bf16(af, bf, acc[c], 0, 0, 0);
        }
    }

    const int b   = (int)(row0 >> 10);
    const int il0 = (int)(row0 & 1023);
    // acc[c][jj] = Wh[row0 + lq*4 + jj][colbase + c*16 + lr]  (C/D map)
    // Bpack target: kt = il0>>5; k = kt*32 + h16*16 + lq*4 + jj
    //   -> lane slot lp = (h16*2 + (lq>>1))*16 + lr, short offset u0 = (lq&1)*4
    const int kt  = il0 >> 5;
    const int h16 = (il0 >> 4) & 1;
    const int lp  = (h16 * 2 + (lq >> 1)) * 16 + lr;
    const int u0  = (lq & 1) * 4;
    short* bpo = Bpack + ((long)b * 16 * 32) * 512;
    #pragma unroll
    for (int c = 0; c < 4; ++c) {
        short4 s;
        s.x = f2bf(acc[c][0]); s.y = f2bf(acc[c][1]);
        s.z = f2bf(acc[c][2]); s.w = f2bf(acc[c][3]);
        int n16 = w * 4 + c;
        *(short4*)(bpo + ((long)(n16 * 32 + kt)) * 512 + lp * 8 + u0) = s;
    }

    float p1[4] = {0.f, 0.f, 0.f, 0.f}, p2[4] = {0.f, 0.f, 0.f, 0.f};
    #pragma unroll
    for (int c = 0; c < 4; ++c) {
        int col = colbase + c * 16 + lr;
        float a1v = a[col], a2v = a[FOUT + col];
        #pragma unroll
        for (int j = 0; j < 4; ++j) { p1[j] += acc[c][j] * a1v; p2[j] += acc[c][j] * a2v; }
    }
    #pragma unroll
    for (int off = 1; off < 16; off <<= 1) {
        #pragma unroll
        for (int j = 0; j < 4; ++j) {
            p1[j] += __shfl_xor(p1[j], off, 64);
            p2[j] += __shfl_xor(p2[j], off, 64);
        }
    }
    if (lr == 0) {
        #pragma unroll
        for (int j = 0; j < 4; ++j) { r1[w][lq * 4 + j] = p1[j]; r2[w][lq * 4 + j] = p2[j]; }
    }
    __syncthreads();
    if (tid < 16) {
        F1[row0 + tid] = r1[0][tid] + r1[1][tid] + r1[2][tid] + r1[3][tid];
        F2[row0 + tid] = r2[0][tid] + r2[1][tid] + r2[2][tid] + r2[3][tid];
    }
}

// ---------------------------------------------------------------------------
// k_pgen: Apack[i][j] = adj ? exp(leaky(f1_i+f2_j)) : 0 (bf16, m=0 softmax),
// written DIRECTLY in A-fragment lane order -> every global write is a
// contiguous 1KB chunk per wave. adj read once via coalesced ballots.
// Block = 256 thr / 4 waves; tile = 16 rows x 1024 j. Grid = (8, 64).
// ---------------------------------------------------------------------------
__global__ __launch_bounds__(256) void k_pgen(const float* __restrict__ adj,
                                              const float* __restrict__ F1,
                                              const float* __restrict__ F2,
                                              short* __restrict__ Apack,
                                              float* __restrict__ lrow) {
    const int tid = threadIdx.x;
    const int b   = blockIdx.x;
    const int m16 = blockIdx.y;
    const int i0  = m16 * 16;
    const int w   = tid >> 6, l = tid & 63;
    const int lr  = l & 15, lq = l >> 4;

    __shared__ float f2s[N_];                     // 4 KB
    __shared__ unsigned long long bits[16][17];   // 2.1 KB (padded)
    __shared__ float lred[4][16];

    { int j = tid * 4; *(float4*)&f2s[j] = *(const float4*)(F2 + b * N_ + j); }

    // ballot-compress adj rows i0..i0+15 (read once, 256B coalesced per instr)
    {
        const float* abase = adj + ((long)b * N_ + i0 + w * 4) * N_;
        #pragma unroll
        for (int rr = 0; rr < 4; ++rr) {
            #pragma unroll
            for (int c = 0; c < 16; ++c) {
                float v = abase[(long)rr * N_ + c * 64 + l];
                unsigned long long mm = __ballot(v > 0.f);
                if (l == 0) bits[w * 4 + rr][c] = mm;
            }
        }
    }
    __syncthreads();

    const float f1 = F1[b * N_ + i0 + lr];
    short* apb = Apack + (((long)b * 64 + m16) * 32) * 512;

    float ls = 0.f;
    #pragma unroll
    for (int it = 0; it < 8; ++it) {
        const int kt = w + it * 4;
        unsigned m8 = (unsigned)(bits[lr][kt >> 1] >> ((kt & 1) * 32 + lq * 8)) & 0xFFu;
        float f2k[8];
        *(float4*)&f2k[0] = *(const float4*)&f2s[kt * 32 + lq * 8];
        *(float4*)&f2k[4] = *(const float4*)&f2s[kt * 32 + lq * 8 + 4];
        bf16x8 pv;
        #pragma unroll
        for (int u = 0; u < 8; ++u) {
            float x = f1 + f2k[u];
            float t = fmaxf(x, ALPHA * x);
            float e = ((m8 >> u) & 1u) ? __expf(t) : 0.f;
            short s = f2bf_fast(e);
            pv[u] = s;
            ls += bf2f(s);
        }
        *(bf16x8*)(apb + (long)kt * 512 + l * 8) = pv;   // 1KB/wave, contiguous
    }

    ls += __shfl_xor(ls, 16, 64);
    ls += __shfl_xor(ls, 32, 64);
    if (lq == 0) lred[w][lr] = ls;
    __syncthreads();
    if (tid < 16)
        lrow[(long)b * N_ + i0 + tid] = lred[0][tid] + lred[1][tid] + lred[2][tid] + lred[3][tid];
}

// ---------------------------------------------------------------------------
// k_pv: h_prime = (Apack @ Bpack)/l + LayerNorm + GELU. All fragment loads
// are contiguous 1KB chunks, register prefetch depth 1. Block = 1024 thr /
// 16 waves = 2 row-groups x 4 col-waves x 2 K-split; grid = (8, 32) ->
// blockIdx.x = batch pins the 2.5MB (Apack+Bpack) slab to one XCD L2.
// 4 waves/SIMD. Cross-K LDS reduce, then LN + exact GELU.
// ---------------------------------------------------------------------------
__global__ __launch_bounds__(1024, 4) void k_pv(const short* __restrict__ Apack,
                                                const short* __restrict__ Bpack,
                                                const float* __restrict__ lrow,
                                                const float* __restrict__ gamma,
                                                const float* __restrict__ beta,
                                                float* __restrict__ out) {
    const int tid = threadIdx.x;
    const int b   = blockIdx.x;
    const int w   = tid >> 6, l = tid & 63;
    const int lr  = l & 15, lq = l >> 4;
    const int cw  = w & 3;          // col wave: cols cw*64..+63
    const int rg  = (w >> 2) & 1;   // row group
    const int kg  = w >> 3;         // K half
    const int m16 = blockIdx.y * 2 + rg;

    __shared__ float sc[2][4][16][68];            // 34.8 KB cross-K partials
    __shared__ float lnp1[2][4][16], lnp2[2][4][16];

    const short* ap = Apack + (((long)b * 64 + m16) * 32 + kg * 16) * 512 + l * 8;
    const short* bp = Bpack + (((long)b * 16 + cw * 4) * 32 + kg * 16) * 512 + l * 8;

    f32x4 acc[4] = {};

    bf16x8 aC = *(const bf16x8*)ap;
    bf16x8 bC0 = *(const bf16x8*)(bp);
    bf16x8 bC1 = *(const bf16x8*)(bp + 32 * 512);
    bf16x8 bC2 = *(const bf16x8*)(bp + 64 * 512);
    bf16x8 bC3 = *(const bf16x8*)(bp + 96 * 512);

    #pragma unroll
    for (int t = 0; t < 16; ++t) {
        bf16x8 aN = aC, bN0 = bC0, bN1 = bC1, bN2 = bC2, bN3 = bC3;
        if (t < 15) {
            aN  = *(const bf16x8*)(ap + (t + 1) * 512);
            bN0 = *(const bf16x8*)(bp + (t + 1) * 512);
            bN1 = *(const bf16x8*)(bp + (32 * 32 + t + 1) * 512 - 32 * 512 * 31);   // placeholder, replaced below
            bN1 = *(const bf16x8*)(bp + (32 + t + 1) * 512);
            bN2 = *(const bf16x8*)(bp + (64 + t + 1) * 512);
            bN3 = *(const bf16x8*)(bp + (96 + t + 1) * 512);
        }
        acc[0] = __builtin_amdgcn_mfma_f32_16x16x32_bf16(aC, bC0, acc[0], 0, 0, 0);
        acc[1] = __builtin_amdgcn_mfma_f32_16x16x32_bf16(aC, bC1, acc[1], 0, 0, 0);
        acc[2] = __builtin_amdgcn_mfma_f32_16x16x32_bf16(aC, bC2, acc[2], 0, 0, 0);
        acc[3] = __builtin_amdgcn_mfma_f32_16x16x32_bf16(aC, bC3, acc[3], 0, 0, 0);
        aC = aN; bC0 = bN0; bC1 = bN1; bC2 = bN2; bC3 = bN3;
    }

    // ---- cross-K reduce: kg=1 waves park partials in LDS ----
    if (kg == 1) {
        #pragma unroll
        for (int cf = 0; cf < 4; ++cf)
            #pragma unroll
            for (int jj = 0; jj < 4; ++jj)
                sc[rg][cw][lq * 4 + jj][cf * 16 + lr] = acc[cf][jj];
    }
    __syncthreads();

    if (kg == 0) {
        #pragma unroll
        for (int cf = 0; cf < 4; ++cf)
            #pragma unroll
            for (int jj = 0; jj < 4; ++jj)
                acc[cf][jj] += sc[rg][cw][lq * 4 + jj][cf * 16 + lr];

        // 1/l for local rows
        float il[4];
        #pragma unroll
        for (int jj = 0; jj < 4; ++jj) {
            float r = lrow[(long)b * N_ + m16 * 16 + lq * 4 + jj];
            il[jj] = (r > 0.f) ? 1.0f / r : 0.f;
        }
        float s1[4] = {0.f,0.f,0.f,0.f}, s2[4] = {0.f,0.f,0.f,0.f};
        #pragma unroll
        for (int cf = 0; cf < 4; ++cf)
            #pragma unroll
            for (int jj = 0; jj < 4; ++jj) {
                float v = acc[cf][jj] * il[jj];
                acc[cf][jj] = v;
                s1[jj] += v;
                s2[jj] += v * v;
            }
        #pragma unroll
        for (int off = 1; off < 16; off <<= 1)
            #pragma unroll
            for (int jj = 0; jj < 4; ++jj) {
                s1[jj] += __shfl_xor(s1[jj], off, 64);
                s2[jj] += __shfl_xor(s2[jj], off, 64);
            }
        if (lr == 0) {
            #pragma unroll
            for (int jj = 0; jj < 4; ++jj) {
                lnp1[rg][cw][lq * 4 + jj] = s1[jj];
                lnp2[rg][cw][lq * 4 + jj] = s2[jj];
            }
        }
    }
    __syncthreads();

    if (kg == 0) {
        #pragma unroll
        for (int jj = 0; jj < 4; ++jj) {
            int row = lq * 4 + jj;
            float t1 = lnp1[rg][0][row] + lnp1[rg][1][row] + lnp1[rg][2][row] + lnp1[rg][3][row];
            float t2 = lnp2[rg][0][row] + lnp2[rg][1][row] + lnp2[rg][2][row] + lnp2[rg][3][row];
            float mu   = t1 * (1.0f / FOUT);
            float rstd = rsqrtf(t2 * (1.0f / FOUT) - mu * mu + EPSV);
            #pragma unroll
            for (int cf = 0; cf < 4; ++cf) {
                int col = cw * 64 + cf * 16 + lr;
                out[((long)b * N_ + m16 * 16 + row) * FOUT + col] =
                    gelu_exact((acc[cf][jj] - mu) * rstd * gamma[col] + beta[col]);
            }
        }
    }
}

extern "C" void kernel_launch(void* const* d_in, const int* in_sizes, int n_in,
                              void* d_out, int out_size, void* d_ws, size_t ws_size,
                              hipStream_t stream) {
    const float* h     = (const float*)d_in[0];
    const float* adj   = (const float*)d_in[1];
    // d_in[2]=q_type, d_in[3]=pos : unused scalars
    const float* W     = (const float*)d_in[4];
    const float* a     = (const float*)d_in[5];
    const float* gamma = (const float*)d_in[6];
    const float* beta  = (const float*)d_in[7];
    float* out = (float*)d_out;

    // workspace layout (~20.4 MB)
    short* Apack = (short*)d_ws;                         // 8*64*32*512 = 16 MB
    short* Bpack = Apack + (size_t)B_ * 64 * 32 * 512;   // 8*16*32*512 = 4 MB
    short* WT    = Bpack + (size_t)B_ * 16 * 32 * 512;   // 256 KB
    float* F1    = (float*)(WT + (size_t)FOUT * FIN);    // 32 KB
    float* F2    = F1 + (size_t)B_ * N_;
    float* lrow  = F2 + (size_t)B_ * N_;

    k_prep<<<dim3(128), 256, 0, stream>>>(W, WT);
    k_wh  <<<dim3(B_ * N_ / 16), 256, 0, stream>>>(h, WT, a, Bpack, F1, F2);
    k_pgen<<<dim3(B_, N_ / 16), 256, 0, stream>>>(adj, F1, F2, Apack, lrow);
    k_pv  <<<dim3(B_, N_ / 32), 1024, 0, stream>>>(Apack, Bpack, lrow, gamma, beta, out);
}

// Round 8
// 60.081 us; speedup vs baseline: 1.5403x; 1.3045x over previous
//
#include <hip/hip_runtime.h>
#include <math.h>

#define B_    8
#define N_    1024
#define FIN   512
#define FOUT  256
#define ALPHA 0.2f
#define EPSV  1e-5f

typedef __attribute__((ext_vector_type(8))) short bf16x8;
typedef __attribute__((ext_vector_type(4))) float f32x4;

__device__ __forceinline__ short f2bf(float x) {          // RNE
    unsigned u = __builtin_bit_cast(unsigned, x);
    u = (u + 0x7FFFu + ((u >> 16) & 1u)) >> 16;
    return (short)u;
}
__device__ __forceinline__ short f2bf_fast(float x) {     // round-half-up (P path)
    unsigned u = __builtin_bit_cast(unsigned, x);
    return (short)((u + 0x8000u) >> 16);
}
__device__ __forceinline__ float bf2f(short s) {
    return __builtin_bit_cast(float, ((unsigned)(unsigned short)s) << 16);
}
__device__ __forceinline__ float gelu_exact(float x) {
    return 0.5f * x * (1.0f + erff(x * 0.70710678118654752f));
}

// Fragment-linear chunk layout (1 KB = 64 lanes x 16B):
//   Apack[b][m16][kt][l][u8] : lane l=(lq*16+lr) holds P[m16*16+lr][kt*32+lq*8+u]
//   Bpack[b][n16][kt][l][u8] : lane l=(lq*16+lr) holds Wh[kt*32+lq*8+u][n16*16+lr]

// ---------------------------------------------------------------------------
// k_prep: W (512x256 fp32 row-major) -> WT (256x512 bf16, [col][k]).
// ---------------------------------------------------------------------------
__global__ __launch_bounds__(256) void k_prep(const float* __restrict__ W,
                                              short* __restrict__ WT) {
    int id  = blockIdx.x * 256 + threadIdx.x;
    int col = id >> 7;
    int k4  = (id & 127) * 4;
    short4 v;
    v.x = f2bf(W[(k4 + 0) * FOUT + col]);
    v.y = f2bf(W[(k4 + 1) * FOUT + col]);
    v.z = f2bf(W[(k4 + 2) * FOUT + col]);
    v.w = f2bf(W[(k4 + 3) * FOUT + col]);
    *(short4*)(WT + (long)col * FIN + k4) = v;
}

// ---------------------------------------------------------------------------
// k_wh: Wh = h @ W via bf16 MFMA; writes Bpack (fragment-linear) + F1/F2.
// Block = 256 thr / 4 waves; 16 node-rows; grid = 512.
// ---------------------------------------------------------------------------
__global__ __launch_bounds__(256) void k_wh(const float* __restrict__ h,
                                            const short* __restrict__ WT,
                                            const float* __restrict__ a,
                                            short* __restrict__ Bpack,
                                            float* __restrict__ F1,
                                            float* __restrict__ F2) {
    const int tid = threadIdx.x;
    const int w   = tid >> 6, l = tid & 63;
    const int lr  = l & 15, lq = l >> 4;
    const long row0 = (long)blockIdx.x * 16;
    const int colbase = w * 64;

    __shared__ float r1[4][16], r2[4][16];

    f32x4 acc[4] = {};
    const float* hrow = h + (row0 + lr) * FIN + lq * 8;

    #pragma unroll
    for (int k0 = 0; k0 < FIN; k0 += 32) {
        float4 v0 = *(const float4*)(hrow + k0);
        float4 v1 = *(const float4*)(hrow + k0 + 4);
        bf16x8 af;
        af[0] = f2bf(v0.x); af[1] = f2bf(v0.y); af[2] = f2bf(v0.z); af[3] = f2bf(v0.w);
        af[4] = f2bf(v1.x); af[5] = f2bf(v1.y); af[6] = f2bf(v1.z); af[7] = f2bf(v1.w);
        #pragma unroll
        for (int c = 0; c < 4; ++c) {
            const short* bp = WT + (long)(colbase + c * 16 + lr) * FIN + k0 + lq * 8;
            bf16x8 bf = *(const bf16x8*)bp;
            acc[c] = __builtin_amdgcn_mfma_f32_16x16x32_bf16(af, bf, acc[c], 0, 0, 0);
        }
    }

    const int b   = (int)(row0 >> 10);
    const int il0 = (int)(row0 & 1023);
    // acc[c][jj] = Wh[row0 + lq*4 + jj][colbase + c*16 + lr]  (C/D map)
    // Bpack: kt = il0>>5; lane slot lp = (h16*2 + (lq>>1))*16 + lr, u0 = (lq&1)*4
    const int kt  = il0 >> 5;
    const int h16 = (il0 >> 4) & 1;
    const int lp  = (h16 * 2 + (lq >> 1)) * 16 + lr;
    const int u0  = (lq & 1) * 4;
    short* bpo = Bpack + ((long)b * 16 * 32) * 512;
    #pragma unroll
    for (int c = 0; c < 4; ++c) {
        short4 s;
        s.x = f2bf(acc[c][0]); s.y = f2bf(acc[c][1]);
        s.z = f2bf(acc[c][2]); s.w = f2bf(acc[c][3]);
        int n16 = w * 4 + c;
        *(short4*)(bpo + ((long)(n16 * 32 + kt)) * 512 + lp * 8 + u0) = s;
    }

    float p1[4] = {0.f, 0.f, 0.f, 0.f}, p2[4] = {0.f, 0.f, 0.f, 0.f};
    #pragma unroll
    for (int c = 0; c < 4; ++c) {
        int col = colbase + c * 16 + lr;
        float a1v = a[col], a2v = a[FOUT + col];
        #pragma unroll
        for (int j = 0; j < 4; ++j) { p1[j] += acc[c][j] * a1v; p2[j] += acc[c][j] * a2v; }
    }
    #pragma unroll
    for (int off = 1; off < 16; off <<= 1) {
        #pragma unroll
        for (int j = 0; j < 4; ++j) {
            p1[j] += __shfl_xor(p1[j], off, 64);
            p2[j] += __shfl_xor(p2[j], off, 64);
        }
    }
    if (lr == 0) {
        #pragma unroll
        for (int j = 0; j < 4; ++j) { r1[w][lq * 4 + j] = p1[j]; r2[w][lq * 4 + j] = p2[j]; }
    }
    __syncthreads();
    if (tid < 16) {
        F1[row0 + tid] = r1[0][tid] + r1[1][tid] + r1[2][tid] + r1[3][tid];
        F2[row0 + tid] = r2[0][tid] + r2[1][tid] + r2[2][tid] + r2[3][tid];
    }
}

// ---------------------------------------------------------------------------
// k_pgen v2: P = adj ? exp(leaky(f1+f2)) : 0 (bf16, m=0 shift-invariant
// softmax), written directly in A-fragment lane order. NO ballots / LDS /
// barriers: lane (lq,lr) loads its own 8 adj values (2 x float4; per-instr
// 16 rows x 64B fully-used segments). Grid = (8, 64, 4) = 2048 blocks,
// 2 kt-chunks per wave -> 32 waves/CU of pure streaming.
// ---------------------------------------------------------------------------
__global__ __launch_bounds__(256) void k_pgen(const float* __restrict__ adj,
                                              const float* __restrict__ F1,
                                              const float* __restrict__ F2,
                                              short* __restrict__ Apack) {
    const int tid = threadIdx.x;
    const int b   = blockIdx.x;
    const int m16 = blockIdx.y;
    const int ktg = blockIdx.z;
    const int w   = tid >> 6, l = tid & 63;
    const int lr  = l & 15, lq = l >> 4;
    const int i0  = m16 * 16;

    const float f1 = F1[b * N_ + i0 + lr];
    const float* __restrict__ arow = adj + ((long)b * N_ + i0 + lr) * N_;
    const float* __restrict__ f2b  = F2 + (long)b * N_;
    short* __restrict__ apb = Apack + (((long)b * 64 + m16) * 32) * 512;

    #pragma unroll
    for (int it = 0; it < 2; ++it) {
        const int kt = ktg * 8 + w * 2 + it;
        const int j0 = kt * 32 + lq * 8;
        float4 a0  = *(const float4*)(arow + j0);
        float4 a1  = *(const float4*)(arow + j0 + 4);
        float4 f20 = *(const float4*)(f2b + j0);
        float4 f21 = *(const float4*)(f2b + j0 + 4);
        float aa[8] = {a0.x, a0.y, a0.z, a0.w, a1.x, a1.y, a1.z, a1.w};
        float ff[8] = {f20.x, f20.y, f20.z, f20.w, f21.x, f21.y, f21.z, f21.w};
        bf16x8 pv;
        #pragma unroll
        for (int u = 0; u < 8; ++u) {
            float x = f1 + ff[u];
            float t = fmaxf(x, ALPHA * x);
            float e = (aa[u] > 0.f) ? __expf(t) : 0.f;
            pv[u] = f2bf_fast(e);
        }
        *(bf16x8*)(apb + (long)kt * 512 + l * 8) = pv;   // 1KB/wave contiguous
    }
}

// ---------------------------------------------------------------------------
// k_pv: h_prime = (Apack @ Bpack)/l + LayerNorm + GELU. All fragment loads
// are contiguous 1KB chunks, register prefetch depth 1. l is computed HERE
// from the A-fragments (VALU pipe is idle; zero extra traffic). Block =
// 1024 thr / 16 waves = 2 row-groups x 4 col-waves x 2 K-split; grid =
// (8, 32) -> blockIdx.x = batch pins the slab to one XCD L2.
// ---------------------------------------------------------------------------
__global__ __launch_bounds__(1024, 4) void k_pv(const short* __restrict__ Apack,
                                                const short* __restrict__ Bpack,
                                                const float* __restrict__ gamma,
                                                const float* __restrict__ beta,
                                                float* __restrict__ out) {
    const int tid = threadIdx.x;
    const int b   = blockIdx.x;
    const int w   = tid >> 6, l = tid & 63;
    const int lr  = l & 15, lq = l >> 4;
    const int cw  = w & 3;          // col wave: cols cw*64..+63
    const int rg  = (w >> 2) & 1;   // row group
    const int kg  = w >> 3;         // K half
    const int m16 = blockIdx.y * 2 + rg;

    __shared__ float sc[2][4][16][68];            // cross-K partials
    __shared__ float lnp1[2][4][16], lnp2[2][4][16];
    __shared__ float lsumS[2][2][16];             // [rg][kg][row]

    const short* ap = Apack + (((long)b * 64 + m16) * 32 + kg * 16) * 512 + l * 8;
    const short* bp = Bpack + (((long)b * 16 + cw * 4) * 32 + kg * 16) * 512 + l * 8;

    f32x4 acc[4] = {};
    float ls = 0.f;

    bf16x8 aC  = *(const bf16x8*)ap;
    bf16x8 bC0 = *(const bf16x8*)(bp);
    bf16x8 bC1 = *(const bf16x8*)(bp + 32 * 512);
    bf16x8 bC2 = *(const bf16x8*)(bp + 64 * 512);
    bf16x8 bC3 = *(const bf16x8*)(bp + 96 * 512);

    #pragma unroll
    for (int t = 0; t < 16; ++t) {
        bf16x8 aN = aC, bN0 = bC0, bN1 = bC1, bN2 = bC2, bN3 = bC3;
        if (t < 15) {
            aN  = *(const bf16x8*)(ap + (t + 1) * 512);
            bN0 = *(const bf16x8*)(bp + (t + 1) * 512);
            bN1 = *(const bf16x8*)(bp + (32 + t + 1) * 512);
            bN2 = *(const bf16x8*)(bp + (64 + t + 1) * 512);
            bN3 = *(const bf16x8*)(bp + (96 + t + 1) * 512);
        }
        #pragma unroll
        for (int u = 0; u < 8; ++u) ls += bf2f(aC[u]);   // l partial (VALU pipe)
        acc[0] = __builtin_amdgcn_mfma_f32_16x16x32_bf16(aC, bC0, acc[0], 0, 0, 0);
        acc[1] = __builtin_amdgcn_mfma_f32_16x16x32_bf16(aC, bC1, acc[1], 0, 0, 0);
        acc[2] = __builtin_amdgcn_mfma_f32_16x16x32_bf16(aC, bC2, acc[2], 0, 0, 0);
        acc[3] = __builtin_amdgcn_mfma_f32_16x16x32_bf16(aC, bC3, acc[3], 0, 0, 0);
        aC = aN; bC0 = bN0; bC1 = bN1; bC2 = bN2; bC3 = bN3;
    }

    // row sums: reduce over lq -> every lane holds sum for row lr (this kg half)
    ls += __shfl_xor(ls, 16, 64);
    ls += __shfl_xor(ls, 32, 64);
    if (cw == 0 && lq == 0) lsumS[rg][kg][lr] = ls;

    // cross-K reduce: kg=1 waves park partials in LDS
    if (kg == 1) {
        #pragma unroll
        for (int cf = 0; cf < 4; ++cf)
            #pragma unroll
            for (int jj = 0; jj < 4; ++jj)
                sc[rg][cw][lq * 4 + jj][cf * 16 + lr] = acc[cf][jj];
    }
    __syncthreads();

    if (kg == 0) {
        #pragma unroll
        for (int cf = 0; cf < 4; ++cf)
            #pragma unroll
            for (int jj = 0; jj < 4; ++jj)
                acc[cf][jj] += sc[rg][cw][lq * 4 + jj][cf * 16 + lr];

        // 1/l for local rows (combine kg halves)
        float il[4];
        #pragma unroll
        for (int jj = 0; jj < 4; ++jj) {
            float r = lsumS[rg][0][lq * 4 + jj] + lsumS[rg][1][lq * 4 + jj];
            il[jj] = (r > 0.f) ? 1.0f / r : 0.f;
        }
        float s1[4] = {0.f,0.f,0.f,0.f}, s2[4] = {0.f,0.f,0.f,0.f};
        #pragma unroll
        for (int cf = 0; cf < 4; ++cf)
            #pragma unroll
            for (int jj = 0; jj < 4; ++jj) {
                float v = acc[cf][jj] * il[jj];
                acc[cf][jj] = v;
                s1[jj] += v;
                s2[jj] += v * v;
            }
        #pragma unroll
        for (int off = 1; off < 16; off <<= 1)
            #pragma unroll
            for (int jj = 0; jj < 4; ++jj) {
                s1[jj] += __shfl_xor(s1[jj], off, 64);
                s2[jj] += __shfl_xor(s2[jj], off, 64);
            }
        if (lr == 0) {
            #pragma unroll
            for (int jj = 0; jj < 4; ++jj) {
                lnp1[rg][cw][lq * 4 + jj] = s1[jj];
                lnp2[rg][cw][lq * 4 + jj] = s2[jj];
            }
        }
    }
    __syncthreads();

    if (kg == 0) {
        #pragma unroll
        for (int jj = 0; jj < 4; ++jj) {
            int row = lq * 4 + jj;
            float t1 = lnp1[rg][0][row] + lnp1[rg][1][row] + lnp1[rg][2][row] + lnp1[rg][3][row];
            float t2 = lnp2[rg][0][row] + lnp2[rg][1][row] + lnp2[rg][2][row] + lnp2[rg][3][row];
            float mu   = t1 * (1.0f / FOUT);
            float rstd = rsqrtf(t2 * (1.0f / FOUT) - mu * mu + EPSV);
            #pragma unroll
            for (int cf = 0; cf < 4; ++cf) {
                int col = cw * 64 + cf * 16 + lr;
                out[((long)b * N_ + m16 * 16 + row) * FOUT + col] =
                    gelu_exact((acc[cf][jj] - mu) * rstd * gamma[col] + beta[col]);
            }
        }
    }
}

extern "C" void kernel_launch(void* const* d_in, const int* in_sizes, int n_in,
                              void* d_out, int out_size, void* d_ws, size_t ws_size,
                              hipStream_t stream) {
    const float* h     = (const float*)d_in[0];
    const float* adj   = (const float*)d_in[1];
    // d_in[2]=q_type, d_in[3]=pos : unused scalars
    const float* W     = (const float*)d_in[4];
    const float* a     = (const float*)d_in[5];
    const float* gamma = (const float*)d_in[6];
    const float* beta  = (const float*)d_in[7];
    float* out = (float*)d_out;

    // workspace layout (~20.4 MB)
    short* Apack = (short*)d_ws;                         // 8*64*32*512 = 16 MB
    short* Bpack = Apack + (size_t)B_ * 64 * 32 * 512;   // 8*16*32*512 = 4 MB
    short* WT    = Bpack + (size_t)B_ * 16 * 32 * 512;   // 256 KB
    float* F1    = (float*)(WT + (size_t)FOUT * FIN);    // 32 KB
    float* F2    = F1 + (size_t)B_ * N_;

    k_prep<<<dim3(128), 256, 0, stream>>>(W, WT);
    k_wh  <<<dim3(B_ * N_ / 16), 256, 0, stream>>>(h, WT, a, Bpack, F1, F2);
    k_pgen<<<dim3(B_, N_ / 16, 4), 256, 0, stream>>>(adj, F1, F2, Apack);
    k_pv  <<<dim3(B_, N_ / 32), 1024, 0, stream>>>(Apack, Bpack, gamma, beta, out);
}